// Round 4
// baseline (242.991 us; speedup 1.0000x reference)
//
#include <hip/hip_runtime.h>

typedef __attribute__((ext_vector_type(8))) __bf16 bf16x8;
typedef __attribute__((ext_vector_type(4))) float f32x4;
typedef __attribute__((ext_vector_type(8))) unsigned short u16x8;
typedef __attribute__((ext_vector_type(4))) unsigned short u16x4;

#define DEV __device__ __forceinline__

DEV float bf2f(unsigned short u) {
  unsigned int x = ((unsigned int)u) << 16;
  return __builtin_bit_cast(float, x);
}
DEV unsigned short f2bf(float f) {
  unsigned int u = __builtin_bit_cast(unsigned int, f);
  u = u + 0x7fffu + ((u >> 16) & 1u);
  return (unsigned short)(u >> 16);
}

DEV void glds16(const void* g, void* l) {
  __builtin_amdgcn_global_load_lds(
      (__attribute__((address_space(1))) void*)g,
      (__attribute__((address_space(3))) void*)l, 16, 0, 0);
}

// ---------------- fp32 -> bf16 convert ----------------
__global__ __launch_bounds__(256) void k_cvt(const float* __restrict__ in,
                                             unsigned short* __restrict__ out,
                                             int n4) {
  int i = blockIdx.x * 256 + threadIdx.x;
  const int stride = gridDim.x * 256;
  for (; i < n4; i += stride) {
    float4 v = reinterpret_cast<const float4*>(in)[i];
    u16x4 o;
    o[0] = f2bf(v.x); o[1] = f2bf(v.y); o[2] = f2bf(v.z); o[3] = f2bf(v.w);
    reinterpret_cast<u16x4*>(out)[i] = o;
  }
}

// ---------------- prompt pad+convert: (8,77,768) f32 -> (8,128,768) bf16 ----------------
__global__ __launch_bounds__(256) void k_pad(const float* __restrict__ prompt,
                                             unsigned short* __restrict__ pb) {
  const int i4 = blockIdx.x * 256 + threadIdx.x;  // 0..196607
  const int e = i4 * 4;
  const int b = e / 98304;
  const int rem = e - b * 98304;
  const int s = rem / 768;
  const int d = rem - s * 768;
  u16x4 o;
  if (s < 77) {
    float4 v = *reinterpret_cast<const float4*>(&prompt[((long)b * 77 + s) * 768 + d]);
    o[0] = f2bf(v.x); o[1] = f2bf(v.y); o[2] = f2bf(v.z); o[3] = f2bf(v.w);
  } else {
    o[0] = 0; o[1] = 0; o[2] = 0; o[3] = 0;
  }
  reinterpret_cast<u16x4*>(pb)[i4] = o;
}

// ---------------- bias concat [bk;bv] ----------------
__global__ __launch_bounds__(256) void k_bcat(const float* __restrict__ bk,
                                              const float* __restrict__ bv,
                                              float* __restrict__ bkv) {
  const int i = blockIdx.x * 256 + threadIdx.x;
  if (i < 768) bkv[i] = bk[i];
  else if (i < 1536) bkv[i] = bv[i - 768];
}

// ---------------- small 128x128 bf16 NT-GEMM (KV projection only) ----------------
template <int BIAS_ROW, int OUT_BF16>
__global__ __launch_bounds__(256, 2) void k_gemm(const unsigned short* __restrict__ A, long sA,
                                                 const unsigned short* __restrict__ B, long sB,
                                                 void* __restrict__ Cv, long sC,
                                                 const float* __restrict__ bias,
                                                 int K, int ldC, int Ncols) {
  __shared__ alignas(16) unsigned short As[128 * 64];
  __shared__ alignas(16) unsigned short Bs[128 * 64];

  const int bz = blockIdx.z;
  const unsigned short* Ab = A + (long)bz * sA;
  const unsigned short* Bb = B + (long)bz * sB;

  const int tid = threadIdx.x;
  const int wave = tid >> 6;
  const int lane = tid & 63;
  const int tm = blockIdx.y * 128;
  const int tn = blockIdx.x * 128;
  const int wm = (wave >> 1) * 64;
  const int wn = (wave & 1) * 64;
  const int fr = lane & 15;
  const int fk = (lane >> 4) * 8;
  const int srow = lane >> 3;
  const int scol = (lane & 7) * 8;

  f32x4 acc[4][4] = {};

  for (int k0 = 0; k0 < K; k0 += 64) {
    __syncthreads();
#pragma unroll
    for (int i = 0; i < 4; ++i) {
      const int chunk = i * 4 + wave;
      glds16(Ab + (long)(tm + chunk * 8 + srow) * K + (k0 + scol), &As[chunk * 512]);
    }
#pragma unroll
    for (int i = 0; i < 4; ++i) {
      const int chunk = i * 4 + wave;
      glds16(Bb + (long)(tn + chunk * 8 + srow) * K + (k0 + scol), &Bs[chunk * 512]);
    }
    __syncthreads();
#pragma unroll
    for (int ks = 0; ks < 2; ++ks) {
      bf16x8 af[4], bf[4];
#pragma unroll
      for (int mi = 0; mi < 4; ++mi)
        af[mi] = *reinterpret_cast<const bf16x8*>(&As[(wm + mi * 16 + fr) * 64 + ks * 32 + fk]);
#pragma unroll
      for (int ni = 0; ni < 4; ++ni)
        bf[ni] = *reinterpret_cast<const bf16x8*>(&Bs[(wn + ni * 16 + fr) * 64 + ks * 32 + fk]);
#pragma unroll
      for (int mi = 0; mi < 4; ++mi)
#pragma unroll
        for (int ni = 0; ni < 4; ++ni)
          acc[mi][ni] =
              __builtin_amdgcn_mfma_f32_16x16x32_bf16(af[mi], bf[ni], acc[mi][ni], 0, 0, 0);
    }
  }

  const int r0 = (lane >> 4) * 4;
#pragma unroll
  for (int mi = 0; mi < 4; ++mi) {
#pragma unroll
    for (int ni = 0; ni < 4; ++ni) {
      const int col = tn + wn + ni * 16 + fr;
      if (col < Ncols) {
#pragma unroll
        for (int r = 0; r < 4; ++r) {
          const int row = tm + wm + mi * 16 + r0 + r;
          const float v = acc[mi][ni][r] + (BIAS_ROW ? bias[row] : bias[col]);
          if (OUT_BF16) {
            ((unsigned short*)Cv)[(long)bz * sC + (long)row * ldC + col] = f2bf(v);
          } else {
            ((float*)Cv)[(long)bz * sC + (long)row * ldC + col] = v;
          }
        }
      }
    }
  }
}

// ============ 256x256 BK=64 phase-interleaved NT-GEMM, counted vmcnt ============
// C[m,n] = sum_k A[m,k] B[n,k] + bias. K fixed = 768 (12 K-tiles).
// 8 waves (2M x 4N), wave tile 128x64. A triple-buffered (prefetch dist 2),
// B double-buffered (dist 1); per tile issue order B[t+1],B[t+1],A[t+2],A[t+2]
// so vmcnt(4) at tile end drains exactly {A[t+1],B[t+1]}. LDS swizzle:
// source col XOR (row&7)*8 elems at stage; same XOR on ds_read -> ~2-way banks.
// QUIRK=1: bf16 out, quirk layout qt[b*3145728 + c*4096 + t] via LDS transpose.
// QUIRK=0: f32 out, out[g*768 + col], bias per col.
template <int QUIRK>
__global__ __launch_bounds__(512, 2) void k_gemm256(const unsigned short* __restrict__ A,
                                                    const unsigned short* __restrict__ B,
                                                    void* __restrict__ Cv,
                                                    const float* __restrict__ bias,
                                                    int ntN) {
  __shared__ alignas(16) unsigned short lds[81920];  // 160 KB
  unsigned short* const As0 = lds;
  unsigned short* const As1 = lds + 16384;
  unsigned short* const As2 = lds + 32768;
  unsigned short* const Bs0 = lds + 49152;
  unsigned short* const Bs1 = lds + 65536;

  const int tid = threadIdx.x;
  const int wv = tid >> 6;
  const int ln = tid & 63;
  const int wm = wv >> 2;        // 0..1 (M)
  const int wn = wv & 3;         // 0..3 (N)
  const int fr = ln & 15;
  const int fg8 = (ln >> 4) * 8;

  // XCD-chunked bijective swizzle (384 blocks, 384%8==0)
  const int bid = blockIdx.x;
  const int swz = (bid & 7) * 48 + (bid >> 3);
  const int mt0 = (swz / ntN) * 256;
  const int nt0 = (swz % ntN) * 256;

  // staging geometry
  const int stRow = wv * 16 + (ln >> 3);             // row within 128-row unit (j=0)
  const int stLds = wv * 1024;                       // elem offset within unit (j=0)
  const int srcsub = ((ln & 7) ^ (ln >> 3)) * 8;     // pre-swizzled source col (elems)

#define STAGE(DST, SRC, ROWBASE, T)                                              \
  {                                                                              \
    unsigned short* _l = (DST) + stLds;                                          \
    const unsigned short* _g = (SRC) + (long)((ROWBASE) + stRow) * 768 +         \
                               (T) * 64 + srcsub;                                \
    glds16(_g, _l);                                                              \
    glds16(_g + 8 * 768, _l + 512);                                              \
  }

  // prologue: A[0] (2 units), B[0] (2), A[1] (2)  -> 12 loads
  STAGE(As0, A, mt0, 0) STAGE(As0 + 8192, A, mt0 + 128, 0)
  STAGE(Bs0, B, nt0, 0) STAGE(Bs0 + 8192, B, nt0 + 128, 0)
  STAGE(As1, A, mt0, 1) STAGE(As1 + 8192, A, mt0 + 128, 1)
  asm volatile("s_waitcnt vmcnt(4)" ::: "memory");
  __builtin_amdgcn_s_barrier();

  f32x4 acc[8][4] = {};
  bf16x8 a[4][2], b[2][2];

#define LDA(MH)                                                                  \
  _Pragma("unroll") for (int i = 0; i < 4; ++i)                                  \
      _Pragma("unroll") for (int ks = 0; ks < 2; ++ks) {                         \
    const int row = wm * 128 + (MH) * 64 + i * 16 + fr;                          \
    a[i][ks] = *reinterpret_cast<const bf16x8*>(                                 \
        &curA[row * 64 + ((ks * 32 + fg8) ^ ((row & 7) * 8))]);                  \
  }
#define LDB(NH)                                                                  \
  _Pragma("unroll") for (int i = 0; i < 2; ++i)                                  \
      _Pragma("unroll") for (int ks = 0; ks < 2; ++ks) {                         \
    const int row = wn * 64 + (NH) * 32 + i * 16 + fr;                           \
    b[i][ks] = *reinterpret_cast<const bf16x8*>(                                 \
        &curB[row * 64 + ((ks * 32 + fg8) ^ ((row & 7) * 8))]);                  \
  }
#define MF(MH, NH)                                                               \
  __builtin_amdgcn_s_setprio(1);                                                 \
  _Pragma("unroll") for (int i = 0; i < 4; ++i)                                  \
      _Pragma("unroll") for (int jn = 0; jn < 2; ++jn)                           \
          _Pragma("unroll") for (int ks = 0; ks < 2; ++ks)                       \
      acc[(MH) * 4 + i][(NH) * 2 + jn] = __builtin_amdgcn_mfma_f32_16x16x32_bf16(\
          a[i][ks], b[jn][ks], acc[(MH) * 4 + i][(NH) * 2 + jn], 0, 0, 0);       \
  __builtin_amdgcn_s_setprio(0);

  int ab = 0, bb = 0;
#pragma unroll 1
  for (int t = 0; t < 12; ++t) {
    unsigned short* curA = (ab == 0) ? As0 : ((ab == 1) ? As1 : As2);
    unsigned short* curB = bb ? Bs1 : Bs0;
    unsigned short* nxtB = bb ? Bs0 : Bs1;
    int a2 = ab + 2; if (a2 >= 3) a2 -= 3;
    unsigned short* pfA = (a2 == 0) ? As0 : ((a2 == 1) ? As1 : As2);
    const bool doB = (t < 11), doA = (t < 10);

    // ph0: LDA(m0), LDB(n0); stage B[t+1] unit0; MFMA (m0,n0)
    LDA(0) LDB(0)
    if (doB) STAGE(nxtB, B, nt0, t + 1)
    __builtin_amdgcn_s_barrier();
    MF(0, 0)
    __builtin_amdgcn_s_barrier();

    // ph1: LDB(n1); stage B[t+1] unit1; MFMA (m0,n1)
    LDB(1)
    if (doB) STAGE(nxtB + 8192, B, nt0 + 128, t + 1)
    __builtin_amdgcn_s_barrier();
    MF(0, 1)
    __builtin_amdgcn_s_barrier();

    // ph2: LDA(m1); stage A[t+2] unit0; MFMA (m1,n1)
    LDA(1)
    if (doA) STAGE(pfA, A, mt0, t + 2)
    __builtin_amdgcn_s_barrier();
    MF(1, 1)
    __builtin_amdgcn_s_barrier();

    // ph3: LDB(n0); stage A[t+2] unit1; MFMA (m1,n0); counted vmcnt
    LDB(0)
    if (doA) STAGE(pfA + 8192, A, mt0 + 128, t + 2)
    __builtin_amdgcn_s_barrier();
    MF(1, 0)
    if (t <= 9) asm volatile("s_waitcnt vmcnt(4)" ::: "memory");
    else        asm volatile("s_waitcnt vmcnt(0)" ::: "memory");
    __builtin_amdgcn_s_barrier();

    ab = (ab + 1 == 3) ? 0 : ab + 1;
    bb ^= 1;
  }

  const int r0 = (ln >> 4) * 4;  // C/D: col=lane&15, row=(lane>>4)*4+reg

  if (QUIRK) {
    // bias + f2bf -> LDS C-tile [c-local 256][t-local 256], then coalesced quirk write
    __syncthreads();
#pragma unroll
    for (int mi = 0; mi < 8; ++mi)
#pragma unroll
      for (int ni = 0; ni < 4; ++ni)
#pragma unroll
        for (int r = 0; r < 4; ++r) {
          const int row = wm * 128 + mi * 16 + r0 + r;
          const int col = wn * 64 + ni * 16 + fr;
          lds[row * 256 + col] = f2bf(acc[mi][ni][r] + bias[mt0 + row]);
        }
    __syncthreads();
    unsigned short* qt = (unsigned short*)Cv;
    const int b_ = nt0 >> 12;
    const int t_off = nt0 & 4095;
    const int row = tid >> 1;
    const int half = (tid & 1) * 128;
    const long gb = (long)b_ * 3145728 + (long)(mt0 + row) * 4096 + t_off + half;
#pragma unroll
    for (int k = 0; k < 16; ++k) {
      const int kk = ((k + row) & 15) * 8;
      *reinterpret_cast<u16x8*>(&qt[gb + kk]) =
          *reinterpret_cast<const u16x8*>(&lds[row * 256 + half + kk]);
    }
  } else {
    float* out = (float*)Cv;
#pragma unroll
    for (int mi = 0; mi < 8; ++mi)
#pragma unroll
      for (int ni = 0; ni < 4; ++ni) {
        const int col = nt0 + wn * 64 + ni * 16 + fr;
        const float bv = bias[col];
#pragma unroll
        for (int r = 0; r < 4; ++r) {
          const long g = mt0 + wm * 128 + mi * 16 + r0 + r;
          out[g * 768 + col] = acc[mi][ni][r] + bv;
        }
      }
  }
#undef STAGE
#undef LDA
#undef LDB
#undef MF
}

// ---------------- MFMA fused cross-attention (unchanged from r3) ----------------
__global__ __launch_bounds__(256, 2) void k_attn(const unsigned short* __restrict__ QT,
                                                 const unsigned short* __restrict__ KVT,
                                                 unsigned short* __restrict__ Y) {
  __shared__ alignas(16) unsigned short Plds[128 * 104];
  __shared__ alignas(16) unsigned short Vt[64 * 104];

  const int b = blockIdx.z;
  const int h = blockIdx.y;
  const int tid = threadIdx.x;
  const int wave = tid >> 6;
  const int lane = tid & 63;
  const int fr = lane & 15;
  const int fg = lane >> 4;

  const long kvb = (long)b * 118272;
  const long kflat = kvb + h * 64;
  const long vflat = kvb + 59136 + h * 64;

  for (int task = tid; task < 1024; task += 256) {
    const int s8 = task & 15;
    if (s8 < 12) {
      const int d = task >> 4;
      u16x8 v;
#pragma unroll
      for (int j = 0; j < 8; ++j) {
        const int s = s8 * 8 + j;
        v[j] = (s < 77) ? KVT[vflat + (long)s * 768 + d] : (unsigned short)0;
      }
      *reinterpret_cast<u16x8*>(&Vt[d * 104 + s8 * 8]) = v;
    }
  }
  {
    const int row = wave * 32 + (lane >> 1);
    u16x8 z = {};
    *reinterpret_cast<u16x8*>(&Plds[row * 104 + 80 + (lane & 1) * 8]) = z;
  }

  const int t0 = blockIdx.x * 128 + wave * 32;
  const long qb = (long)b * 3145728 + h * 64;

  bf16x8 qa[2][2];
#pragma unroll
  for (int m = 0; m < 2; ++m)
#pragma unroll
    for (int ks = 0; ks < 2; ++ks)
      qa[m][ks] = *reinterpret_cast<const bf16x8*>(
          &QT[qb + (long)(t0 + m * 16 + fr) * 768 + ks * 32 + fg * 8]);

  bf16x8 kb[5][2];
#pragma unroll
  for (int n = 0; n < 5; ++n)
#pragma unroll
    for (int ks = 0; ks < 2; ++ks)
      kb[n][ks] = *reinterpret_cast<const bf16x8*>(
          &KVT[kflat + (long)(n * 16 + fr) * 768 + ks * 32 + fg * 8]);

  f32x4 s_[2][5] = {};
#pragma unroll
  for (int ks = 0; ks < 2; ++ks)
#pragma unroll
    for (int m = 0; m < 2; ++m)
#pragma unroll
      for (int n = 0; n < 5; ++n)
        s_[m][n] = __builtin_amdgcn_mfma_f32_16x16x32_bf16(qa[m][ks], kb[n][ks], s_[m][n], 0, 0, 0);

  const float scale = 0.036084391824351615f;  // 1/sqrt(768) (quirk: d_prompt)
  f32x4 rl[2];
#pragma unroll
  for (int m = 0; m < 2; ++m) {
#pragma unroll
    for (int n = 0; n < 5; ++n) {
      const int key = n * 16 + fr;
#pragma unroll
      for (int r = 0; r < 4; ++r)
        s_[m][n][r] = (key < 77) ? __expf(s_[m][n][r] * scale) : 0.f;
    }
    f32x4 t = s_[m][0] + s_[m][1] + s_[m][2] + s_[m][3] + s_[m][4];
#pragma unroll
    for (int w = 1; w < 16; w <<= 1) {
      f32x4 u;
#pragma unroll
      for (int r = 0; r < 4; ++r) u[r] = __shfl_xor(t[r], w);
      t += u;
    }
    rl[m][0] = 1.f / t[0]; rl[m][1] = 1.f / t[1];
    rl[m][2] = 1.f / t[2]; rl[m][3] = 1.f / t[3];
  }

#pragma unroll
  for (int m = 0; m < 2; ++m)
#pragma unroll
    for (int n = 0; n < 5; ++n)
#pragma unroll
      for (int r = 0; r < 4; ++r)
        Plds[(wave * 32 + m * 16 + fg * 4 + r) * 104 + n * 16 + fr] = f2bf(s_[m][n][r]);

  __syncthreads();

  f32x4 o[2][4] = {};
#pragma unroll
  for (int ks = 0; ks < 3; ++ks) {
    bf16x8 pa[2], vb[4];
#pragma unroll
    for (int m = 0; m < 2; ++m)
      pa[m] = *reinterpret_cast<const bf16x8*>(
          &Plds[(wave * 32 + m * 16 + fr) * 104 + ks * 32 + fg * 8]);
#pragma unroll
    for (int n = 0; n < 4; ++n)
      vb[n] = *reinterpret_cast<const bf16x8*>(&Vt[(n * 16 + fr) * 104 + ks * 32 + fg * 8]);
#pragma unroll
    for (int m = 0; m < 2; ++m)
#pragma unroll
      for (int n = 0; n < 4; ++n)
        o[m][n] = __builtin_amdgcn_mfma_f32_16x16x32_bf16(pa[m], vb[n], o[m][n], 0, 0, 0);
  }

#pragma unroll
  for (int m = 0; m < 2; ++m)
#pragma unroll
    for (int n = 0; n < 4; ++n)
#pragma unroll
      for (int r = 0; r < 4; ++r) {
        const int t = t0 + m * 16 + fg * 4 + r;
        const int d = n * 16 + fr;
        Y[qb + (long)t * 768 + d] = f2bf(o[m][n][r] * rl[m][r]);
      }
}

// ---------------- launch ----------------
extern "C" void kernel_launch(void* const* d_in, const int* in_sizes, int n_in,
                              void* d_out, int out_size, void* d_ws, size_t ws_size,
                              hipStream_t stream) {
  const float* x      = (const float*)d_in[0];
  const float* prompt = (const float*)d_in[1];
  const float* Wq     = (const float*)d_in[2];
  const float* bq     = (const float*)d_in[3];
  const float* Wk     = (const float*)d_in[4];
  const float* bk     = (const float*)d_in[5];
  const float* Wv     = (const float*)d_in[6];
  const float* bv     = (const float*)d_in[7];
  const float* Wp     = (const float*)d_in[8];
  const float* bp     = (const float*)d_in[9];
  float* out = (float*)d_out;

  if (ws_size < 108853248u) return;
  char* ws = (char*)d_ws;
  unsigned short* xb   = (unsigned short*)(ws + 0);           // 50,331,648 B
  unsigned short* y    = xb;                                  // alias (xb dead after Q-GEMM)
  unsigned short* qt   = (unsigned short*)(ws + 50331648L);
  unsigned short* wqb  = (unsigned short*)(ws + 100663296L);
  unsigned short* wpb  = (unsigned short*)(ws + 101842944L);
  unsigned short* wkvb = (unsigned short*)(ws + 103022592L);
  unsigned short* pb   = (unsigned short*)(ws + 105381888L);
  unsigned short* kvt  = (unsigned short*)(ws + 106954752L);
  float*          bkv  = (float*)(ws + 108847104L);

  k_cvt<<<2048, 256, 0, stream>>>(x, xb, 25165824 / 4);
  k_cvt<<<576, 256, 0, stream>>>(Wq, wqb, 589824 / 4);
  k_cvt<<<576, 256, 0, stream>>>(Wp, wpb, 589824 / 4);
  k_cvt<<<576, 256, 0, stream>>>(Wk, wkvb, 589824 / 4);
  k_cvt<<<576, 256, 0, stream>>>(Wv, wkvb + 589824, 589824 / 4);
  k_pad<<<768, 256, 0, stream>>>(prompt, pb);
  k_bcat<<<6, 256, 0, stream>>>(bk, bv, bkv);

  // KV: rows = [Wk;Wv] channels (1536), cols = 77 keys -> kvt[b][c*77+s] (K|V blocks)
  k_gemm<1, 1><<<dim3(1, 12, 8), 256, 0, stream>>>(wkvb, 0L, pb, 98304L, kvt, 118272L,
                                                   bkv, 768, 77, 77);

  // Q: A=Wq (768,768), B=xb flattened (32768,768); quirk bf16 out into qt
  k_gemm256<1><<<384, 512, 0, stream>>>(wqb, xb, qt, bq, 128);

  k_attn<<<dim3(32, 12, 8), 256, 0, stream>>>(qt, kvt, y);

  // out: A=y flattened (32768,768), B=Wp (768,768); f32 out, bias per col
  k_gemm256<0><<<384, 512, 0, stream>>>(y, wpb, out, bp, 3);
}

// Round 5
// 236.999 us; speedup vs baseline: 1.0253x; 1.0253x over previous
//
#include <hip/hip_runtime.h>

typedef __attribute__((ext_vector_type(8))) __bf16 bf16x8;
typedef __attribute__((ext_vector_type(4))) float f32x4;
typedef __attribute__((ext_vector_type(8))) unsigned short u16x8;
typedef __attribute__((ext_vector_type(4))) unsigned short u16x4;

#define DEV __device__ __forceinline__

DEV float bf2f(unsigned short u) {
  unsigned int x = ((unsigned int)u) << 16;
  return __builtin_bit_cast(float, x);
}
DEV unsigned short f2bf(float f) {
  unsigned int u = __builtin_bit_cast(unsigned int, f);
  u = u + 0x7fffu + ((u >> 16) & 1u);
  return (unsigned short)(u >> 16);
}

DEV void glds16(const void* g, void* l) {
  __builtin_amdgcn_global_load_lds(
      (__attribute__((address_space(1))) void*)g,
      (__attribute__((address_space(3))) void*)l, 16, 0, 0);
}

// ---------------- one-shot prep: 4 weight cvts + prompt pad + bias concat ----------------
// blocks [0,2304): weight cvt (576 blocks each for Wq,Wk,Wv,Wp)
// blocks [2304,3072): prompt (8,77,768) f32 -> (8,128,768) bf16 zero-padded
// blocks [3072,3078): bkv = [bk;bv]
__global__ __launch_bounds__(256) void k_prep(
    const float* __restrict__ Wq, const float* __restrict__ Wk,
    const float* __restrict__ Wv, const float* __restrict__ Wp,
    const float* __restrict__ prompt, const float* __restrict__ bk,
    const float* __restrict__ bv,
    unsigned short* __restrict__ wqb, unsigned short* __restrict__ wkvb,
    unsigned short* __restrict__ wpb, unsigned short* __restrict__ pb,
    float* __restrict__ bkv) {
  const int blk = blockIdx.x;
  const int tid = threadIdx.x;
  if (blk < 2304) {
    const int w = blk / 576;  // 0:Wq 1:Wk 2:Wv 3:Wp
    const int i = (blk - w * 576) * 256 + tid;  // < 147456 float4 units
    const float* src = (w == 0) ? Wq : (w == 1) ? Wk : (w == 2) ? Wv : Wp;
    unsigned short* dst =
        (w == 0) ? wqb : (w == 1) ? wkvb : (w == 2) ? (wkvb + 589824) : wpb;
    float4 v = reinterpret_cast<const float4*>(src)[i];
    u16x4 o;
    o[0] = f2bf(v.x); o[1] = f2bf(v.y); o[2] = f2bf(v.z); o[3] = f2bf(v.w);
    reinterpret_cast<u16x4*>(dst)[i] = o;
  } else if (blk < 3072) {
    const int i4 = (blk - 2304) * 256 + tid;  // < 196608
    const int e = i4 * 4;
    const int b = e / 98304;
    const int rem = e - b * 98304;
    const int s = rem / 768;
    const int d = rem - s * 768;
    u16x4 o;
    if (s < 77) {
      float4 v = *reinterpret_cast<const float4*>(&prompt[((long)b * 77 + s) * 768 + d]);
      o[0] = f2bf(v.x); o[1] = f2bf(v.y); o[2] = f2bf(v.z); o[3] = f2bf(v.w);
    } else {
      o[0] = 0; o[1] = 0; o[2] = 0; o[3] = 0;
    }
    reinterpret_cast<u16x4*>(pb)[i4] = o;
  } else {
    const int i = (blk - 3072) * 256 + tid;  // < 1536
    bkv[i] = (i < 768) ? bk[i] : bv[i - 768];
  }
}

// ---------------- bf16 NT-GEMM: C[m,n] = sum_k A[m,k]*B[n,k] + bias ----------------
// 128x128 tile, BK=64, 4 waves (2x2), 4x4 frags of 16x16x32. Used for KV + out GEMMs.
template <int BIAS_ROW, int OUT_BF16>
__global__ __launch_bounds__(256, 2) void k_gemm(const unsigned short* __restrict__ A, long sA,
                                                 const unsigned short* __restrict__ B, long sB,
                                                 void* __restrict__ Cv, long sC,
                                                 const float* __restrict__ bias,
                                                 int K, int ldC, int Ncols) {
  __shared__ alignas(16) unsigned short As[128 * 64];
  __shared__ alignas(16) unsigned short Bs[128 * 64];

  const int bz = blockIdx.z;
  const unsigned short* Ab = A + (long)bz * sA;
  const unsigned short* Bb = B + (long)bz * sB;

  const int tid = threadIdx.x;
  const int wave = tid >> 6;
  const int lane = tid & 63;
  const int tm = blockIdx.y * 128;
  const int tn = blockIdx.x * 128;
  const int wm = (wave >> 1) * 64;
  const int wn = (wave & 1) * 64;
  const int fr = lane & 15;
  const int fk = (lane >> 4) * 8;
  const int srow = lane >> 3;
  const int scol = (lane & 7) * 8;

  f32x4 acc[4][4] = {};

  for (int k0 = 0; k0 < K; k0 += 64) {
    __syncthreads();
#pragma unroll
    for (int i = 0; i < 4; ++i) {
      const int chunk = i * 4 + wave;
      glds16(Ab + (long)(tm + chunk * 8 + srow) * K + (k0 + scol), &As[chunk * 512]);
    }
#pragma unroll
    for (int i = 0; i < 4; ++i) {
      const int chunk = i * 4 + wave;
      glds16(Bb + (long)(tn + chunk * 8 + srow) * K + (k0 + scol), &Bs[chunk * 512]);
    }
    __syncthreads();
#pragma unroll
    for (int ks = 0; ks < 2; ++ks) {
      bf16x8 af[4], bf[4];
#pragma unroll
      for (int mi = 0; mi < 4; ++mi)
        af[mi] = *reinterpret_cast<const bf16x8*>(&As[(wm + mi * 16 + fr) * 64 + ks * 32 + fk]);
#pragma unroll
      for (int ni = 0; ni < 4; ++ni)
        bf[ni] = *reinterpret_cast<const bf16x8*>(&Bs[(wn + ni * 16 + fr) * 64 + ks * 32 + fk]);
#pragma unroll
      for (int mi = 0; mi < 4; ++mi)
#pragma unroll
        for (int ni = 0; ni < 4; ++ni)
          acc[mi][ni] =
              __builtin_amdgcn_mfma_f32_16x16x32_bf16(af[mi], bf[ni], acc[mi][ni], 0, 0, 0);
    }
  }

  const int r0 = (lane >> 4) * 4;  // C/D: col=lane&15, row=(lane>>4)*4+reg
#pragma unroll
  for (int mi = 0; mi < 4; ++mi) {
#pragma unroll
    for (int ni = 0; ni < 4; ++ni) {
      const int col = tn + wn + ni * 16 + fr;
      if (col < Ncols) {
#pragma unroll
        for (int r = 0; r < 4; ++r) {
          const int row = tm + wm + mi * 16 + r0 + r;
          const float v = acc[mi][ni][r] + (BIAS_ROW ? bias[row] : bias[col]);
          if (OUT_BF16) {
            ((unsigned short*)Cv)[(long)bz * sC + (long)row * ldC + col] = f2bf(v);
          } else {
            ((float*)Cv)[(long)bz * sC + (long)row * ldC + col] = v;
          }
        }
      }
    }
  }
}

// ---------------- Q-projection GEMM with fused f32->bf16 B-staging ----------------
// A = Wq bf16 (768,768) via glds16; B = x f32 (per-batch 4096x768) reg-staged with
// on-the-fly cvt into the SAME LDS layout glds16 would produce (lane*8 elems/chunk).
// C quirk layout: qt[bz*3145728 + c*4096 + t] bf16, bias per c-row.
__global__ __launch_bounds__(256, 2) void k_qgemm(const unsigned short* __restrict__ A,
                                                  const float* __restrict__ X,
                                                  unsigned short* __restrict__ qt,
                                                  const float* __restrict__ bias) {
  __shared__ alignas(16) unsigned short As[128 * 64];
  __shared__ alignas(16) unsigned short Bs[128 * 64];

  const int bz = blockIdx.z;
  const float* Xb = X + (long)bz * 3145728;

  const int tid = threadIdx.x;
  const int wave = tid >> 6;
  const int lane = tid & 63;
  const int tm = blockIdx.y * 128;  // c (6 tiles)
  const int tn = blockIdx.x * 128;  // t (32 tiles)
  const int wm = (wave >> 1) * 64;
  const int wn = (wave & 1) * 64;
  const int fr = lane & 15;
  const int fk = (lane >> 4) * 8;
  const int srow = lane >> 3;
  const int scol = (lane & 7) * 8;

  f32x4 acc[4][4] = {};

  for (int k0 = 0; k0 < 768; k0 += 64) {
    __syncthreads();
#pragma unroll
    for (int i = 0; i < 4; ++i) {
      const int chunk = i * 4 + wave;
      glds16(A + (long)(tm + chunk * 8 + srow) * 768 + (k0 + scol), &As[chunk * 512]);
    }
    // B: load 8 f32 of x, convert, ds_write_b128 to the glds-equivalent address
#pragma unroll
    for (int i = 0; i < 4; ++i) {
      const int chunk = i * 4 + wave;
      const float* src = Xb + (long)(tn + chunk * 8 + srow) * 768 + (k0 + scol);
      float4 u = *reinterpret_cast<const float4*>(src);
      float4 v = *reinterpret_cast<const float4*>(src + 4);
      bf16x8 w;
      w[0] = (__bf16)u.x; w[1] = (__bf16)u.y; w[2] = (__bf16)u.z; w[3] = (__bf16)u.w;
      w[4] = (__bf16)v.x; w[5] = (__bf16)v.y; w[6] = (__bf16)v.z; w[7] = (__bf16)v.w;
      *reinterpret_cast<bf16x8*>(&Bs[chunk * 512 + lane * 8]) = w;
    }
    __syncthreads();
#pragma unroll
    for (int ks = 0; ks < 2; ++ks) {
      bf16x8 af[4], bf[4];
#pragma unroll
      for (int mi = 0; mi < 4; ++mi)
        af[mi] = *reinterpret_cast<const bf16x8*>(&As[(wm + mi * 16 + fr) * 64 + ks * 32 + fk]);
#pragma unroll
      for (int ni = 0; ni < 4; ++ni)
        bf[ni] = *reinterpret_cast<const bf16x8*>(&Bs[(wn + ni * 16 + fr) * 64 + ks * 32 + fk]);
#pragma unroll
      for (int mi = 0; mi < 4; ++mi)
#pragma unroll
        for (int ni = 0; ni < 4; ++ni)
          acc[mi][ni] =
              __builtin_amdgcn_mfma_f32_16x16x32_bf16(af[mi], bf[ni], acc[mi][ni], 0, 0, 0);
    }
  }

  const int r0 = (lane >> 4) * 4;
#pragma unroll
  for (int mi = 0; mi < 4; ++mi) {
#pragma unroll
    for (int ni = 0; ni < 4; ++ni) {
      const int col = tn + wn + ni * 16 + fr;  // t
#pragma unroll
      for (int r = 0; r < 4; ++r) {
        const int row = tm + wm + mi * 16 + r0 + r;  // c
        qt[(long)bz * 3145728 + (long)row * 4096 + col] = f2bf(acc[mi][ni][r] + bias[row]);
      }
    }
  }
}

// ---------------- MFMA fused cross-attention (unchanged from r3) ----------------
// Quirk-flat addressing: q(b,h,t,d)=QTflat[b*3145728 + t*768 + h*64 + d]
// k/v from kvt[b][ K-block(59136) | V-block(59136) ] same flat rule.
__global__ __launch_bounds__(256, 2) void k_attn(const unsigned short* __restrict__ QT,
                                                 const unsigned short* __restrict__ KVT,
                                                 unsigned short* __restrict__ Y) {
  __shared__ alignas(16) unsigned short Plds[128 * 104];
  __shared__ alignas(16) unsigned short Vt[64 * 104];

  const int b = blockIdx.z;
  const int h = blockIdx.y;
  const int tid = threadIdx.x;
  const int wave = tid >> 6;
  const int lane = tid & 63;
  const int fr = lane & 15;
  const int fg = lane >> 4;

  const long kvb = (long)b * 118272;
  const long kflat = kvb + h * 64;
  const long vflat = kvb + 59136 + h * 64;

  for (int task = tid; task < 1024; task += 256) {
    const int s8 = task & 15;
    if (s8 < 12) {
      const int d = task >> 4;
      u16x8 v;
#pragma unroll
      for (int j = 0; j < 8; ++j) {
        const int s = s8 * 8 + j;
        v[j] = (s < 77) ? KVT[vflat + (long)s * 768 + d] : (unsigned short)0;
      }
      *reinterpret_cast<u16x8*>(&Vt[d * 104 + s8 * 8]) = v;
    }
  }
  {
    const int row = wave * 32 + (lane >> 1);
    u16x8 z = {};
    *reinterpret_cast<u16x8*>(&Plds[row * 104 + 80 + (lane & 1) * 8]) = z;
  }

  const int t0 = blockIdx.x * 128 + wave * 32;
  const long qb = (long)b * 3145728 + h * 64;

  bf16x8 qa[2][2];
#pragma unroll
  for (int m = 0; m < 2; ++m)
#pragma unroll
    for (int ks = 0; ks < 2; ++ks)
      qa[m][ks] = *reinterpret_cast<const bf16x8*>(
          &QT[qb + (long)(t0 + m * 16 + fr) * 768 + ks * 32 + fg * 8]);

  bf16x8 kb[5][2];
#pragma unroll
  for (int n = 0; n < 5; ++n)
#pragma unroll
    for (int ks = 0; ks < 2; ++ks)
      kb[n][ks] = *reinterpret_cast<const bf16x8*>(
          &KVT[kflat + (long)(n * 16 + fr) * 768 + ks * 32 + fg * 8]);

  f32x4 s_[2][5] = {};
#pragma unroll
  for (int ks = 0; ks < 2; ++ks)
#pragma unroll
    for (int m = 0; m < 2; ++m)
#pragma unroll
      for (int n = 0; n < 5; ++n)
        s_[m][n] = __builtin_amdgcn_mfma_f32_16x16x32_bf16(qa[m][ks], kb[n][ks], s_[m][n], 0, 0, 0);

  const float scale = 0.036084391824351615f;  // 1/sqrt(768) (quirk: d_prompt)
  f32x4 rl[2];
#pragma unroll
  for (int m = 0; m < 2; ++m) {
#pragma unroll
    for (int n = 0; n < 5; ++n) {
      const int key = n * 16 + fr;
#pragma unroll
      for (int r = 0; r < 4; ++r)
        s_[m][n][r] = (key < 77) ? __expf(s_[m][n][r] * scale) : 0.f;
    }
    f32x4 t = s_[m][0] + s_[m][1] + s_[m][2] + s_[m][3] + s_[m][4];
#pragma unroll
    for (int w = 1; w < 16; w <<= 1) {
      f32x4 u;
#pragma unroll
      for (int r = 0; r < 4; ++r) u[r] = __shfl_xor(t[r], w);
      t += u;
    }
    rl[m][0] = 1.f / t[0]; rl[m][1] = 1.f / t[1];
    rl[m][2] = 1.f / t[2]; rl[m][3] = 1.f / t[3];
  }

#pragma unroll
  for (int m = 0; m < 2; ++m)
#pragma unroll
    for (int n = 0; n < 5; ++n)
#pragma unroll
      for (int r = 0; r < 4; ++r)
        Plds[(wave * 32 + m * 16 + fg * 4 + r) * 104 + n * 16 + fr] = f2bf(s_[m][n][r]);

  __syncthreads();

  f32x4 o[2][4] = {};
#pragma unroll
  for (int ks = 0; ks < 3; ++ks) {
    bf16x8 pa[2], vb[4];
#pragma unroll
    for (int m = 0; m < 2; ++m)
      pa[m] = *reinterpret_cast<const bf16x8*>(
          &Plds[(wave * 32 + m * 16 + fr) * 104 + ks * 32 + fg * 8]);
#pragma unroll
    for (int n = 0; n < 4; ++n)
      vb[n] = *reinterpret_cast<const bf16x8*>(&Vt[(n * 16 + fr) * 104 + ks * 32 + fg * 8]);
#pragma unroll
    for (int m = 0; m < 2; ++m)
#pragma unroll
      for (int n = 0; n < 4; ++n)
        o[m][n] = __builtin_amdgcn_mfma_f32_16x16x32_bf16(pa[m], vb[n], o[m][n], 0, 0, 0);
  }

#pragma unroll
  for (int m = 0; m < 2; ++m)
#pragma unroll
    for (int n = 0; n < 4; ++n)
#pragma unroll
      for (int r = 0; r < 4; ++r) {
        const int t = t0 + m * 16 + fg * 4 + r;
        const int d = n * 16 + fr;
        Y[qb + (long)t * 768 + d] = f2bf(o[m][n][r] * rl[m][r]);
      }
}

// ---------------- launch ----------------
extern "C" void kernel_launch(void* const* d_in, const int* in_sizes, int n_in,
                              void* d_out, int out_size, void* d_ws, size_t ws_size,
                              hipStream_t stream) {
  const float* x      = (const float*)d_in[0];
  const float* prompt = (const float*)d_in[1];
  const float* Wq     = (const float*)d_in[2];
  const float* bq     = (const float*)d_in[3];
  const float* Wk     = (const float*)d_in[4];
  const float* bk     = (const float*)d_in[5];
  const float* Wv     = (const float*)d_in[6];
  const float* bv     = (const float*)d_in[7];
  const float* Wp     = (const float*)d_in[8];
  const float* bp     = (const float*)d_in[9];
  float* out = (float*)d_out;

  if (ws_size < 108853248u) return;
  char* ws = (char*)d_ws;
  unsigned short* y    = (unsigned short*)(ws + 0);           // 50,331,648 B
  unsigned short* qt   = (unsigned short*)(ws + 50331648L);   // 50,331,648 B
  unsigned short* wqb  = (unsigned short*)(ws + 100663296L);
  unsigned short* wpb  = (unsigned short*)(ws + 101842944L);
  unsigned short* wkvb = (unsigned short*)(ws + 103022592L);
  unsigned short* pb   = (unsigned short*)(ws + 105381888L);
  unsigned short* kvt  = (unsigned short*)(ws + 106954752L);
  float*          bkv  = (float*)(ws + 108847104L);

  k_prep<<<3078, 256, 0, stream>>>(Wq, Wk, Wv, Wp, prompt, bk, bv,
                                   wqb, wkvb, wpb, pb, bkv);

  // KV: rows = [Wk;Wv] channels (1536), cols = 77 keys -> kvt[b][c*77+s] (K|V blocks)
  k_gemm<1, 1><<<dim3(1, 12, 8), 256, 0, stream>>>(wkvb, 0L, pb, 98304L, kvt, 118272L,
                                                   bkv, 768, 77, 77);

  // Q: quirk GEMM with fused x cvt; qt[b][c*4096+t]
  k_qgemm<<<dim3(32, 6, 8), 256, 0, stream>>>(wqb, x, qt, bq);

  k_attn<<<dim3(32, 12, 8), 256, 0, stream>>>(qt, kvt, y);

  // O[t,c] = Y[t,:]·Wp[c,:] + bp[c] : f32 out, bias per col
  k_gemm<0, 0><<<dim3(6, 32, 8), 256, 0, stream>>>(y, 3145728L, wpb, 0L, out, 3145728L,
                                                   bp, 768, 768, 768);
}

// Round 6
// 225.037 us; speedup vs baseline: 1.0798x; 1.0532x over previous
//
#include <hip/hip_runtime.h>

typedef __attribute__((ext_vector_type(8))) __bf16 bf16x8;
typedef __attribute__((ext_vector_type(4))) float f32x4;
typedef __attribute__((ext_vector_type(8))) unsigned short u16x8;
typedef __attribute__((ext_vector_type(4))) unsigned short u16x4;

#define DEV __device__ __forceinline__

DEV float bf2f(unsigned short u) {
  unsigned int x = ((unsigned int)u) << 16;
  return __builtin_bit_cast(float, x);
}
DEV unsigned short f2bf(float f) {
  unsigned int u = __builtin_bit_cast(unsigned int, f);
  u = u + 0x7fffu + ((u >> 16) & 1u);
  return (unsigned short)(u >> 16);
}

DEV void glds16(const void* g, void* l) {
  __builtin_amdgcn_global_load_lds(
      (__attribute__((address_space(1))) void*)g,
      (__attribute__((address_space(3))) void*)l, 16, 0, 0);
}

// ---------------- one-shot prep: x cvt + 4 weight cvts + prompt pad + bias concat ------
// [0,2048): x grid-stride cvt (12 iters); [2048,2624) Wq; [2624,3200) Wk;
// [3200,3776) Wv; [3776,4352) Wp; [4352,5120) prompt pad; [5120,5126) bkv.
__global__ __launch_bounds__(256) void k_prep(
    const float* __restrict__ x, const float* __restrict__ Wq,
    const float* __restrict__ Wk, const float* __restrict__ Wv,
    const float* __restrict__ Wp, const float* __restrict__ prompt,
    const float* __restrict__ bk, const float* __restrict__ bv,
    unsigned short* __restrict__ xb, unsigned short* __restrict__ wqb,
    unsigned short* __restrict__ wkvb, unsigned short* __restrict__ wpb,
    unsigned short* __restrict__ pb, float* __restrict__ bkv) {
  const int blk = blockIdx.x;
  const int tid = threadIdx.x;
  if (blk < 2048) {
    for (int i = blk * 256 + tid; i < 6291456; i += 524288) {
      float4 v = reinterpret_cast<const float4*>(x)[i];
      u16x4 o;
      o[0] = f2bf(v.x); o[1] = f2bf(v.y); o[2] = f2bf(v.z); o[3] = f2bf(v.w);
      reinterpret_cast<u16x4*>(xb)[i] = o;
    }
  } else if (blk < 4352) {
    const int w = (blk - 2048) / 576;  // 0:Wq 1:Wk 2:Wv 3:Wp
    const int i = (blk - 2048 - w * 576) * 256 + tid;
    const float* src = (w == 0) ? Wq : (w == 1) ? Wk : (w == 2) ? Wv : Wp;
    unsigned short* dst =
        (w == 0) ? wqb : (w == 1) ? wkvb : (w == 2) ? (wkvb + 589824) : wpb;
    float4 v = reinterpret_cast<const float4*>(src)[i];
    u16x4 o;
    o[0] = f2bf(v.x); o[1] = f2bf(v.y); o[2] = f2bf(v.z); o[3] = f2bf(v.w);
    reinterpret_cast<u16x4*>(dst)[i] = o;
  } else if (blk < 5120) {
    const int i4 = (blk - 4352) * 256 + tid;  // < 196608
    const int e = i4 * 4;
    const int b = e / 98304;
    const int rem = e - b * 98304;
    const int s = rem / 768;
    const int d = rem - s * 768;
    u16x4 o;
    if (s < 77) {
      float4 v = *reinterpret_cast<const float4*>(&prompt[((long)b * 77 + s) * 768 + d]);
      o[0] = f2bf(v.x); o[1] = f2bf(v.y); o[2] = f2bf(v.z); o[3] = f2bf(v.w);
    } else {
      o[0] = 0; o[1] = 0; o[2] = 0; o[3] = 0;
    }
    reinterpret_cast<u16x4*>(pb)[i4] = o;
  } else {
    const int i = (blk - 5120) * 256 + tid;
    bkv[i] = (i < 768) ? bk[i] : bv[i - 768];
  }
}

// ---------------- small 128x128 bf16 NT-GEMM (KV projection only) ----------------
template <int BIAS_ROW, int OUT_BF16>
__global__ __launch_bounds__(256, 2) void k_gemm(const unsigned short* __restrict__ A, long sA,
                                                 const unsigned short* __restrict__ B, long sB,
                                                 void* __restrict__ Cv, long sC,
                                                 const float* __restrict__ bias,
                                                 int K, int ldC, int Ncols) {
  __shared__ alignas(16) unsigned short As[128 * 64];
  __shared__ alignas(16) unsigned short Bs[128 * 64];

  const int bz = blockIdx.z;
  const unsigned short* Ab = A + (long)bz * sA;
  const unsigned short* Bb = B + (long)bz * sB;

  const int tid = threadIdx.x;
  const int wave = tid >> 6;
  const int lane = tid & 63;
  const int tm = blockIdx.y * 128;
  const int tn = blockIdx.x * 128;
  const int wm = (wave >> 1) * 64;
  const int wn = (wave & 1) * 64;
  const int fr = lane & 15;
  const int fk = (lane >> 4) * 8;
  const int srow = lane >> 3;
  const int scol = (lane & 7) * 8;

  f32x4 acc[4][4] = {};

  for (int k0 = 0; k0 < K; k0 += 64) {
    __syncthreads();
#pragma unroll
    for (int i = 0; i < 4; ++i) {
      const int chunk = i * 4 + wave;
      glds16(Ab + (long)(tm + chunk * 8 + srow) * K + (k0 + scol), &As[chunk * 512]);
    }
#pragma unroll
    for (int i = 0; i < 4; ++i) {
      const int chunk = i * 4 + wave;
      glds16(Bb + (long)(tn + chunk * 8 + srow) * K + (k0 + scol), &Bs[chunk * 512]);
    }
    __syncthreads();
#pragma unroll
    for (int ks = 0; ks < 2; ++ks) {
      bf16x8 af[4], bf[4];
#pragma unroll
      for (int mi = 0; mi < 4; ++mi)
        af[mi] = *reinterpret_cast<const bf16x8*>(&As[(wm + mi * 16 + fr) * 64 + ks * 32 + fk]);
#pragma unroll
      for (int ni = 0; ni < 4; ++ni)
        bf[ni] = *reinterpret_cast<const bf16x8*>(&Bs[(wn + ni * 16 + fr) * 64 + ks * 32 + fk]);
#pragma unroll
      for (int mi = 0; mi < 4; ++mi)
#pragma unroll
        for (int ni = 0; ni < 4; ++ni)
          acc[mi][ni] =
              __builtin_amdgcn_mfma_f32_16x16x32_bf16(af[mi], bf[ni], acc[mi][ni], 0, 0, 0);
    }
  }

  const int r0 = (lane >> 4) * 4;
#pragma unroll
  for (int mi = 0; mi < 4; ++mi) {
#pragma unroll
    for (int ni = 0; ni < 4; ++ni) {
      const int col = tn + wn + ni * 16 + fr;
      if (col < Ncols) {
#pragma unroll
        for (int r = 0; r < 4; ++r) {
          const int row = tm + wm + mi * 16 + r0 + r;
          const float v = acc[mi][ni][r] + (BIAS_ROW ? bias[row] : bias[col]);
          if (OUT_BF16) {
            ((unsigned short*)Cv)[(long)bz * sC + (long)row * ldC + col] = f2bf(v);
          } else {
            ((float*)Cv)[(long)bz * sC + (long)row * ldC + col] = v;
          }
        }
      }
    }
  }
}

// ============ 256x256 BK=64 4-phase/K-tile counted-vmcnt NT-GEMM ============
// C[m,n] = sum_k A[m,k] B[n,k] + bias; K = 768 (12 K-tiles). 8 waves (2M x 4N),
// wave tile 128x64. A triple-buffered (stage distance 2), B double-buffered
// (distance 1). Per tile t: ph0-1 stage B(t+1) (4 loads), ph2-3 stage A(t+2)
// (4 loads); boundary s_waitcnt vmcnt(4) retires exactly {A(t+1),B(t+1)} and
// keeps A(t+2) in flight (never drains to 0 until t=10). Raw s_barrier only.
// LDS XOR-swizzle: source col ^ (row&7)*8 elems at stage, same XOR on ds_read.
// QUIRK=1: A=Wq, B=xb flat (32768,768); bf16 out qt[b*3145728+c*4096+t], bias/row.
// QUIRK=0: A=y flat, B=Wp; f32 out out[g*768+col], bias/col.
template <int QUIRK>
__global__ __launch_bounds__(512) void k_gemm8(const unsigned short* __restrict__ A,
                                               const unsigned short* __restrict__ B,
                                               void* __restrict__ Cv,
                                               const float* __restrict__ bias) {
  __shared__ alignas(16) unsigned short S[81920];  // 160 KB: A0,A1,A2,B0,B1

  const int tid = threadIdx.x;
  const int wv = tid >> 6;
  const int ln = tid & 63;
  const int wm = wv >> 2;   // 0..1
  const int wn = wv & 3;    // 0..3
  const int fr = ln & 15;
  const int fg8 = (ln >> 4) * 8;
  const int srcx = ((ln & 7) ^ (ln >> 3)) * 8;  // inverse-swizzled source col

  // XCD-chunked bijective swizzle (grid 384, 384%8==0): same-XCD neighbors
  // share the big-operand panel (3 consecutive swz share one 256-panel).
  const int bid = blockIdx.x;
  const int swz = (bid & 7) * 48 + (bid >> 3);
  const int mt = QUIRK ? (swz % 3) : (swz / 3);
  const int nt = QUIRK ? (swz / 3) : (swz % 3);
  const int m0 = mt * 256, n0 = nt * 256;

#define STG(DST, G, ROWB, K0, J)                                          \
  {                                                                       \
    const int u = wv + (J) * 8;                                           \
    glds16((G) + (long)((ROWB) + u * 8 + (ln >> 3)) * 768 + (K0) + srcx,  \
           (DST) + u * 512);                                              \
  }

  // prologue: A0(4), B0(4), A1(4); vmcnt(4) -> A0,B0 resident, A1 in flight
  STG(S, A, m0, 0, 0) STG(S, A, m0, 0, 1) STG(S, A, m0, 0, 2) STG(S, A, m0, 0, 3)
  STG(S + 49152, B, n0, 0, 0) STG(S + 49152, B, n0, 0, 1)
  STG(S + 49152, B, n0, 0, 2) STG(S + 49152, B, n0, 0, 3)
  STG(S + 16384, A, m0, 64, 0) STG(S + 16384, A, m0, 64, 1)
  STG(S + 16384, A, m0, 64, 2) STG(S + 16384, A, m0, 64, 3)
  asm volatile("s_waitcnt vmcnt(4)" ::: "memory");
  __builtin_amdgcn_s_barrier();

  f32x4 acc[8][4] = {};
  bf16x8 a[4][2], b0[2][2], b1[2][2];

#define LDA(MH)                                                           \
  _Pragma("unroll") for (int i = 0; i < 4; ++i)                           \
      _Pragma("unroll") for (int ks = 0; ks < 2; ++ks) {                  \
    const int rl = wm * 128 + (MH) * 64 + i * 16 + fr;                    \
    a[i][ks] = *reinterpret_cast<const bf16x8*>(                          \
        &Ab_[rl * 64 + ((ks * 32 + fg8) ^ ((rl & 7) * 8))]);              \
  }
#define LDB(NH, BV)                                                       \
  _Pragma("unroll") for (int j = 0; j < 2; ++j)                           \
      _Pragma("unroll") for (int ks = 0; ks < 2; ++ks) {                  \
    const int rl = wn * 64 + (NH) * 32 + j * 16 + fr;                     \
    BV[j][ks] = *reinterpret_cast<const bf16x8*>(                         \
        &Bb_[rl * 64 + ((ks * 32 + fg8) ^ ((rl & 7) * 8))]);              \
  }
#define MFQ(MH, NH, BV)                                                   \
  __builtin_amdgcn_s_setprio(1);                                          \
  _Pragma("unroll") for (int i = 0; i < 4; ++i)                           \
      _Pragma("unroll") for (int j = 0; j < 2; ++j)                       \
          _Pragma("unroll") for (int ks = 0; ks < 2; ++ks)                \
      acc[(MH) * 4 + i][(NH) * 2 + j] =                                   \
          __builtin_amdgcn_mfma_f32_16x16x32_bf16(                        \
              a[i][ks], BV[j][ks], acc[(MH) * 4 + i][(NH) * 2 + j],       \
              0, 0, 0);                                                   \
  __builtin_amdgcn_s_setprio(0);
#define BAR __builtin_amdgcn_s_barrier();

  int ab = 0;
#pragma unroll 1
  for (int t = 0; t < 12; ++t) {
    const unsigned short* Ab_ = S + 16384 * ab;
    int abn = ab + 2; if (abn >= 3) abn -= 3;
    unsigned short* AbN = S + 16384 * abn;
    const int bc = t & 1;
    const unsigned short* Bb_ = S + 49152 + 16384 * bc;
    unsigned short* BbN = S + 49152 + 16384 * (bc ^ 1);
    const bool doB = (t < 11), doA = (t < 10);
    const int kB = (t + 1) * 64, kA = (t + 2) * 64;

    // ph0
    LDA(0) LDB(0, b0)
    if (doB) { STG(BbN, B, n0, kB, 0) STG(BbN, B, n0, kB, 1) }
    BAR MFQ(0, 0, b0) BAR
    // ph1
    LDB(1, b1)
    if (doB) { STG(BbN, B, n0, kB, 2) STG(BbN, B, n0, kB, 3) }
    BAR MFQ(0, 1, b1) BAR
    // ph2
    LDA(1)
    if (doA) { STG(AbN, A, m0, kA, 0) STG(AbN, A, m0, kA, 1) }
    BAR MFQ(1, 1, b1) BAR
    // ph3
    if (doA) { STG(AbN, A, m0, kA, 2) STG(AbN, A, m0, kA, 3) }
    BAR MFQ(1, 0, b0)
    if (t <= 9) asm volatile("s_waitcnt vmcnt(4)" ::: "memory");
    else if (t == 10) asm volatile("s_waitcnt vmcnt(0)" ::: "memory");
    BAR

    ab = (ab + 1 == 3) ? 0 : ab + 1;
  }

  const int r0 = (ln >> 4) * 4;  // C/D: col=lane&15, row=(lane>>4)*4+reg

  if (QUIRK) {
    __syncthreads();
#pragma unroll
    for (int mi = 0; mi < 8; ++mi)
#pragma unroll
      for (int ni = 0; ni < 4; ++ni)
#pragma unroll
        for (int r = 0; r < 4; ++r) {
          const int row = wm * 128 + mi * 16 + r0 + r;
          const int col = wn * 64 + ni * 16 + fr;
          S[row * 256 + col] = f2bf(acc[mi][ni][r] + bias[m0 + row]);
        }
    __syncthreads();
    unsigned short* qt = (unsigned short*)Cv;
    const int b_ = n0 >> 12;
    const int t_off = n0 & 4095;
    const int row = tid >> 1;
    const int half = (tid & 1) * 128;
    const long gb = (long)b_ * 3145728 + (long)(m0 + row) * 4096 + t_off + half;
#pragma unroll
    for (int k = 0; k < 16; ++k) {
      const int kk = ((k + row) & 15) * 8;
      *reinterpret_cast<u16x8*>(&qt[gb + kk]) =
          *reinterpret_cast<const u16x8*>(&S[row * 256 + half + kk]);
    }
  } else {
    float* out = (float*)Cv;
#pragma unroll
    for (int mi = 0; mi < 8; ++mi)
#pragma unroll
      for (int ni = 0; ni < 4; ++ni) {
        const int col = n0 + wn * 64 + ni * 16 + fr;
        const float bv = bias[col];
#pragma unroll
        for (int r = 0; r < 4; ++r) {
          const long g = m0 + wm * 128 + mi * 16 + r0 + r;
          out[g * 768 + col] = acc[mi][ni][r] + bv;
        }
      }
  }
#undef STG
#undef LDA
#undef LDB
#undef MFQ
#undef BAR
}

// ---------------- MFMA fused cross-attention (unchanged) ----------------
__global__ __launch_bounds__(256, 2) void k_attn(const unsigned short* __restrict__ QT,
                                                 const unsigned short* __restrict__ KVT,
                                                 unsigned short* __restrict__ Y) {
  __shared__ alignas(16) unsigned short Plds[128 * 104];
  __shared__ alignas(16) unsigned short Vt[64 * 104];

  const int b = blockIdx.z;
  const int h = blockIdx.y;
  const int tid = threadIdx.x;
  const int wave = tid >> 6;
  const int lane = tid & 63;
  const int fr = lane & 15;
  const int fg = lane >> 4;

  const long kvb = (long)b * 118272;
  const long kflat = kvb + h * 64;
  const long vflat = kvb + 59136 + h * 64;

  for (int task = tid; task < 1024; task += 256) {
    const int s8 = task & 15;
    if (s8 < 12) {
      const int d = task >> 4;
      u16x8 v;
#pragma unroll
      for (int j = 0; j < 8; ++j) {
        const int s = s8 * 8 + j;
        v[j] = (s < 77) ? KVT[vflat + (long)s * 768 + d] : (unsigned short)0;
      }
      *reinterpret_cast<u16x8*>(&Vt[d * 104 + s8 * 8]) = v;
    }
  }
  {
    const int row = wave * 32 + (lane >> 1);
    u16x8 z = {};
    *reinterpret_cast<u16x8*>(&Plds[row * 104 + 80 + (lane & 1) * 8]) = z;
  }

  const int t0 = blockIdx.x * 128 + wave * 32;
  const long qb = (long)b * 3145728 + h * 64;

  bf16x8 qa[2][2];
#pragma unroll
  for (int m = 0; m < 2; ++m)
#pragma unroll
    for (int ks = 0; ks < 2; ++ks)
      qa[m][ks] = *reinterpret_cast<const bf16x8*>(
          &QT[qb + (long)(t0 + m * 16 + fr) * 768 + ks * 32 + fg * 8]);

  bf16x8 kb[5][2];
#pragma unroll
  for (int n = 0; n < 5; ++n)
#pragma unroll
    for (int ks = 0; ks < 2; ++ks)
      kb[n][ks] = *reinterpret_cast<const bf16x8*>(
          &KVT[kflat + (long)(n * 16 + fr) * 768 + ks * 32 + fg * 8]);

  f32x4 s_[2][5] = {};
#pragma unroll
  for (int ks = 0; ks < 2; ++ks)
#pragma unroll
    for (int m = 0; m < 2; ++m)
#pragma unroll
      for (int n = 0; n < 5; ++n)
        s_[m][n] = __builtin_amdgcn_mfma_f32_16x16x32_bf16(qa[m][ks], kb[n][ks], s_[m][n], 0, 0, 0);

  const float scale = 0.036084391824351615f;  // 1/sqrt(768) (quirk: d_prompt)
  f32x4 rl[2];
#pragma unroll
  for (int m = 0; m < 2; ++m) {
#pragma unroll
    for (int n = 0; n < 5; ++n) {
      const int key = n * 16 + fr;
#pragma unroll
      for (int r = 0; r < 4; ++r)
        s_[m][n][r] = (key < 77) ? __expf(s_[m][n][r] * scale) : 0.f;
    }
    f32x4 t = s_[m][0] + s_[m][1] + s_[m][2] + s_[m][3] + s_[m][4];
#pragma unroll
    for (int w = 1; w < 16; w <<= 1) {
      f32x4 u;
#pragma unroll
      for (int r = 0; r < 4; ++r) u[r] = __shfl_xor(t[r], w);
      t += u;
    }
    rl[m][0] = 1.f / t[0]; rl[m][1] = 1.f / t[1];
    rl[m][2] = 1.f / t[2]; rl[m][3] = 1.f / t[3];
  }

#pragma unroll
  for (int m = 0; m < 2; ++m)
#pragma unroll
    for (int n = 0; n < 5; ++n)
#pragma unroll
      for (int r = 0; r < 4; ++r)
        Plds[(wave * 32 + m * 16 + fg * 4 + r) * 104 + n * 16 + fr] = f2bf(s_[m][n][r]);

  __syncthreads();

  f32x4 o[2][4] = {};
#pragma unroll
  for (int ks = 0; ks < 3; ++ks) {
    bf16x8 pa[2], vb[4];
#pragma unroll
    for (int m = 0; m < 2; ++m)
      pa[m] = *reinterpret_cast<const bf16x8*>(
          &Plds[(wave * 32 + m * 16 + fr) * 104 + ks * 32 + fg * 8]);
#pragma unroll
    for (int n = 0; n < 4; ++n)
      vb[n] = *reinterpret_cast<const bf16x8*>(&Vt[(n * 16 + fr) * 104 + ks * 32 + fg * 8]);
#pragma unroll
    for (int m = 0; m < 2; ++m)
#pragma unroll
      for (int n = 0; n < 4; ++n)
        o[m][n] = __builtin_amdgcn_mfma_f32_16x16x32_bf16(pa[m], vb[n], o[m][n], 0, 0, 0);
  }

#pragma unroll
  for (int m = 0; m < 2; ++m)
#pragma unroll
    for (int n = 0; n < 4; ++n)
#pragma unroll
      for (int r = 0; r < 4; ++r) {
        const int t = t0 + m * 16 + fg * 4 + r;
        const int d = n * 16 + fr;
        Y[qb + (long)t * 768 + d] = f2bf(o[m][n][r] * rl[m][r]);
      }
}

// ---------------- launch ----------------
extern "C" void kernel_launch(void* const* d_in, const int* in_sizes, int n_in,
                              void* d_out, int out_size, void* d_ws, size_t ws_size,
                              hipStream_t stream) {
  const float* x      = (const float*)d_in[0];
  const float* prompt = (const float*)d_in[1];
  const float* Wq     = (const float*)d_in[2];
  const float* bq     = (const float*)d_in[3];
  const float* Wk     = (const float*)d_in[4];
  const float* bk     = (const float*)d_in[5];
  const float* Wv     = (const float*)d_in[6];
  const float* bv     = (const float*)d_in[7];
  const float* Wp     = (const float*)d_in[8];
  const float* bp     = (const float*)d_in[9];
  float* out = (float*)d_out;

  if (ws_size < 108853248u) return;
  char* ws = (char*)d_ws;
  unsigned short* xb   = (unsigned short*)(ws + 0);           // 50,331,648 B
  unsigned short* y    = xb;                                  // alias (xb dead after Q-GEMM)
  unsigned short* qt   = (unsigned short*)(ws + 50331648L);
  unsigned short* wqb  = (unsigned short*)(ws + 100663296L);
  unsigned short* wpb  = (unsigned short*)(ws + 101842944L);
  unsigned short* wkvb = (unsigned short*)(ws + 103022592L);
  unsigned short* pb   = (unsigned short*)(ws + 105381888L);
  unsigned short* kvt  = (unsigned short*)(ws + 106954752L);
  float*          bkv  = (float*)(ws + 108847104L);

  k_prep<<<5126, 256, 0, stream>>>(x, Wq, Wk, Wv, Wp, prompt, bk, bv,
                                   xb, wqb, wkvb, wpb, pb, bkv);

  // KV: rows = [Wk;Wv] channels (1536), cols = 77 keys -> kvt[b][c*77+s]
  k_gemm<1, 1><<<dim3(1, 12, 8), 256, 0, stream>>>(wkvb, 0L, pb, 98304L, kvt, 118272L,
                                                   bkv, 768, 77, 77);

  // Q: A=Wq (768,768), B=xb flat (32768,768); quirk bf16 out into qt
  k_gemm8<1><<<384, 512, 0, stream>>>(wqb, xb, qt, bq);

  k_attn<<<dim3(32, 12, 8), 256, 0, stream>>>(qt, kvt, y);

  // out: A=y flat (32768,768), B=Wp (768,768); f32 out, bias per col
  k_gemm8<0><<<384, 512, 0, stream>>>(y, wpb, out, bp);
}